// Round 1
// baseline (765.942 us; speedup 1.0000x reference)
//
#include <hip/hip_runtime.h>

namespace {

constexpr int   kB     = 32768;
constexpr int   kT     = 50;
constexpr float kDT    = 0.01f;
constexpr float kGamma = 0.1f;
constexpr float kSigma = 0.2f;
constexpr float kTau   = 0.5f;

// tanh(x) = 1 - 2/(exp(2x)+1), via v_exp_f32 (base-2) + v_rcp_f32.
// Saturates correctly: x>>0 -> exp2->inf -> rcp->0 -> 1; x<<0 -> -1.
__device__ __forceinline__ float ftanh(float x) {
  float e = exp2f(x * 2.8853900817779268f);   // 2*log2(e)
  return 1.0f - 2.0f * __builtin_amdgcn_rcpf(e + 1.0f);
}

__global__ __launch_bounds__(128) void bsde_kernel(
    const float* __restrict__ dw,  const float* __restrict__ X0,
    const float* __restrict__ A,   const float* __restrict__ Bm,
    const float* __restrict__ Cm,  const float* __restrict__ Dm,
    const float* __restrict__ pW1, const float* __restrict__ pb1,
    const float* __restrict__ pW2, const float* __restrict__ pb2,
    const float* __restrict__ pW3, const float* __restrict__ pb3,
    const float* __restrict__ zW1, const float* __restrict__ zb1,
    const float* __restrict__ zW2, const float* __restrict__ zb2,
    const float* __restrict__ zW3, const float* __restrict__ zb3,
    const float* __restrict__ yW1, const float* __restrict__ yb1,
    const float* __restrict__ yW2, const float* __restrict__ yb2,
    const float* __restrict__ yW3, const float* __restrict__ yb3,
    float* __restrict__ out)
{
  // Odd leading strides -> conflict-free b32 LDS access (17,11,9 all odd).
  __shared__ float XS [64][17];
  __shared__ float YS [64][17];
  __shared__ float H1Z[64][11];
  __shared__ float H1P[64][11];
  __shared__ float H2Z[64][11];
  __shared__ float H2P[64][11];
  __shared__ float ZVS[64][17];
  __shared__ float US [64][9];

  const int lane = threadIdx.x & 63;
  // Force wave id into an SGPR so all weight addresses are provably uniform
  // -> compiler emits s_load (scalar cache) instead of per-lane vector loads.
  const int q  = __builtin_amdgcn_readfirstlane((int)(threadIdx.x >> 6));
  const int e  = blockIdx.x * 64 + lane;   // batch element (one per lane, 2 waves/element-group)
  const int r5 = 5 * q;                    // row base, 10-wide layers
  const int r8 = 8 * q;                    // row base, 16-wide vectors
  const int r4 = 4 * q;                    // row base, 8-wide vectors

  // ---------------- load X0 (full 16) ----------------
  float xf[16];
#pragma unroll
  for (int i = 0; i < 16; ++i) xf[i] = X0[e * 16 + i];

  // ---------------- Y0 = MLP_Y0(X0), row-split ----------------
  float hl[5];
#pragma unroll
  for (int r = 0; r < 5; ++r) {
    const int row = r5 + r;
    float s = yb1[row];
#pragma unroll
    for (int k = 0; k < 16; ++k) s += xf[k] * yW1[k * 10 + row];
    hl[r] = ftanh(s);
  }
#pragma unroll
  for (int r = 0; r < 5; ++r) H1Z[lane][r5 + r] = hl[r];
  __syncthreads();
  float h1[10];
#pragma unroll
  for (int k = 0; k < 10; ++k) h1[k] = H1Z[lane][k];

#pragma unroll
  for (int r = 0; r < 5; ++r) {
    const int row = r5 + r;
    float s = yb2[row];
#pragma unroll
    for (int k = 0; k < 10; ++k) s += h1[k] * yW2[k * 10 + row];
    hl[r] = ftanh(s);
  }
#pragma unroll
  for (int r = 0; r < 5; ++r) H2Z[lane][r5 + r] = hl[r];
  __syncthreads();
  float h2[10];
#pragma unroll
  for (int k = 0; k < 10; ++k) h2[k] = H2Z[lane][k];

  float Xh[8], Yh[8];
#pragma unroll
  for (int r = 0; r < 8; ++r) {
    const int row = r8 + r;
    float s = yb3[row];
#pragma unroll
    for (int k = 0; k < 10; ++k) s += h2[k] * yW3[k * 16 + row];
    Yh[r] = s;
    Xh[r] = xf[row];
  }

  float lcp = 0.0f;

  // ---------------- time loop (sequential) ----------------
#pragma unroll 1
  for (int t = 0; t < kT; ++t) {
    const float tv  = (float)t * kDT;
    const float wt  = (t == 0 || t == kT - 1) ? 1.0f : 2.0f;
    const float dwv = dw[t * kB + e];

    // R1: exchange X,Y halves
#pragma unroll
    for (int r = 0; r < 8; ++r) { XS[lane][r8 + r] = Xh[r]; YS[lane][r8 + r] = Yh[r]; }
    __syncthreads();
    float yf[16];
#pragma unroll
    for (int k = 0; k < 16; ++k) { xf[k] = XS[lane][k]; yf[k] = YS[lane][k]; }

    // L1 of both MLPs (state = [t, X]), rows r5..r5+4
    float az[5], ap[5];
#pragma unroll
    for (int r = 0; r < 5; ++r) {
      const int row = r5 + r;
      float sz = zb1[row] + tv * zW1[row];
      float sp = pb1[row] + tv * pW1[row];
#pragma unroll
      for (int k = 0; k < 16; ++k) {
        sz += xf[k] * zW1[(k + 1) * 10 + row];
        sp += xf[k] * pW1[(k + 1) * 10 + row];
      }
      az[r] = ftanh(sz);
      ap[r] = ftanh(sp);
    }
#pragma unroll
    for (int r = 0; r < 5; ++r) { H1Z[lane][r5 + r] = az[r]; H1P[lane][r5 + r] = ap[r]; }
    __syncthreads();
    float h1z[10], h1p[10];
#pragma unroll
    for (int k = 0; k < 10; ++k) { h1z[k] = H1Z[lane][k]; h1p[k] = H1P[lane][k]; }

    // L2
#pragma unroll
    for (int r = 0; r < 5; ++r) {
      const int row = r5 + r;
      float sz = zb2[row];
      float sp = pb2[row];
#pragma unroll
      for (int k = 0; k < 10; ++k) {
        sz += h1z[k] * zW2[k * 10 + row];
        sp += h1p[k] * pW2[k * 10 + row];
      }
      az[r] = ftanh(sz);
      ap[r] = ftanh(sp);
    }
#pragma unroll
    for (int r = 0; r < 5; ++r) { H2Z[lane][r5 + r] = az[r]; H2P[lane][r5 + r] = ap[r]; }
    __syncthreads();
    float h2z[10], h2p[10];
#pragma unroll
    for (int k = 0; k < 10; ++k) { h2z[k] = H2Z[lane][k]; h2p[k] = H2P[lane][k]; }

    // L3: Zv rows r8..r8+7, u rows r4..r4+3 (written straight to LDS)
#pragma unroll
    for (int r = 0; r < 8; ++r) {
      const int row = r8 + r;
      float s = zb3[row];
#pragma unroll
      for (int k = 0; k < 10; ++k) s += h2z[k] * zW3[k * 16 + row];
      ZVS[lane][row] = s;
    }
#pragma unroll
    for (int r = 0; r < 4; ++r) {
      const int row = r4 + r;
      float s = pb3[row];
#pragma unroll
      for (int k = 0; k < 10; ++k) s += h2p[k] * pW3[k * 8 + row];
      US[lane][row] = s;
    }
    __syncthreads();
    float zv[16], uf[8];
#pragma unroll
    for (int k = 0; k < 16; ++k) zv[k] = ZVS[lane][k];
#pragma unroll
    for (int k = 0; k < 8; ++k)  uf[k] = US[lane][k];

    // State updates, rows r8..r8+7
#pragma unroll
    for (int r = 0; r < 8; ++r) {
      const int i = r8 + r;
      float dx = kGamma, fx = kSigma;
#pragma unroll
      for (int j = 0; j < 16; ++j) {
        dx += A [i * 16 + j] * xf[j];     // (X @ A^T)[i]
        fx += Cm[i * 16 + j] * xf[j];     // (X @ C^T)[i]
      }
#pragma unroll
      for (int j = 0; j < 8; ++j) {
        dx += Bm[i * 8 + j] * uf[j];      // (u @ B^T)[i]
        fx += Dm[i * 8 + j] * uf[j];      // (u @ D^T)[i]
      }
      float dy = xf[i];
#pragma unroll
      for (int j = 0; j < 16; ++j) {
        dy += yf[j] * A[j * 16 + i]       // (Y @ A)[i]
            + zv[j] * Cm[j * 16 + i];     // (Zv @ C)[i]
      }
      Xh[r] = xf[i] + kDT * dx + dwv * fx;
      Yh[r] = yf[i] - kDT * dy + dwv * zv[i];
    }

    // Control loss: dH rows r4..r4+3; (u - pre_phi) = tau*dH
    float s2 = 0.0f;
#pragma unroll
    for (int r = 0; r < 4; ++r) {
      const int i = r4 + r;
      float dh = uf[i];
#pragma unroll
      for (int j = 0; j < 16; ++j) dh += yf[j] * Bm[j * 8 + i] + zv[j] * Dm[j * 8 + i];
      s2 += dh * dh;
    }
    lcp += (0.5f * kDT * kTau * kTau) * wt * s2;
  }

  // Per-element loss halves -> wave reduce -> atomics
  float bp = 0.0f;
#pragma unroll
  for (int r = 0; r < 8; ++r) { float d = Yh[r] - Xh[r]; bp += d * d; }

#pragma unroll
  for (int s = 32; s > 0; s >>= 1) {
    bp  += __shfl_down(bp,  s, 64);
    lcp += __shfl_down(lcp, s, 64);
  }
  if (lane == 0) {
    atomicAdd(&out[0], bp  * (1.0f / (float)kB));
    atomicAdd(&out[1], lcp * (1.0f / (float)kB));
  }
}

} // namespace

extern "C" void kernel_launch(void* const* d_in, const int* in_sizes, int n_in,
                              void* d_out, int out_size, void* d_ws, size_t ws_size,
                              hipStream_t stream) {
  (void)in_sizes; (void)n_in; (void)d_ws; (void)ws_size; (void)out_size;

  const float* dw  = (const float*)d_in[0];
  const float* X0  = (const float*)d_in[1];
  const float* A   = (const float*)d_in[2];
  const float* Bm  = (const float*)d_in[3];
  const float* Cm  = (const float*)d_in[4];
  const float* Dm  = (const float*)d_in[5];
  const float* pW1 = (const float*)d_in[6];
  const float* pb1 = (const float*)d_in[7];
  const float* pW2 = (const float*)d_in[8];
  const float* pb2 = (const float*)d_in[9];
  const float* pW3 = (const float*)d_in[10];
  const float* pb3 = (const float*)d_in[11];
  const float* zW1 = (const float*)d_in[12];
  const float* zb1 = (const float*)d_in[13];
  const float* zW2 = (const float*)d_in[14];
  const float* zb2 = (const float*)d_in[15];
  const float* zW3 = (const float*)d_in[16];
  const float* zb3 = (const float*)d_in[17];
  const float* yW1 = (const float*)d_in[18];
  const float* yb1 = (const float*)d_in[19];
  const float* yW2 = (const float*)d_in[20];
  const float* yb2 = (const float*)d_in[21];
  const float* yW3 = (const float*)d_in[22];
  const float* yb3 = (const float*)d_in[23];
  float* out = (float*)d_out;

  hipMemsetAsync(out, 0, 2 * sizeof(float), stream);

  bsde_kernel<<<kB / 64, 128, 0, stream>>>(
      dw, X0, A, Bm, Cm, Dm,
      pW1, pb1, pW2, pb2, pW3, pb3,
      zW1, zb1, zW2, zb2, zW3, zb3,
      yW1, yb1, yW2, yb2, yW3, yb3,
      out);
}

// Round 3
// 384.810 us; speedup vs baseline: 1.9904x; 1.9904x over previous
//
#include <hip/hip_runtime.h>

namespace {

constexpr int   kB     = 32768;
constexpr int   kT     = 50;
constexpr float kDT    = 0.01f;
constexpr float kGamma = 0.1f;
constexpr float kSigma = 0.2f;
constexpr float kTau   = 0.5f;

// Packed-weight workspace layout (float offsets).
constexpr int WS_L1  = 0;              // [4 waves][5 rows][20]  bias, w_t, w_x0..15, pad2
constexpr int WS_L2  = WS_L1  + 400;   // [4][5][12]             bias, w0..9, pad
constexpr int WS_L3  = WS_L2  + 240;   // [4][8][12]             bias, w0..9, pad (waves 2,3 use 4 rows)
constexpr int WS_UPD = WS_L3  + 384;   // [4][4][80]             Arow16 Brow8 Crow16 Drow8 Acol16 Ccol16
constexpr int WS_DH  = WS_UPD + 1280;  // [4][2][32]             Bcol16 Dcol16
constexpr int WS_TOTAL = WS_DH + 256;  // 2560 floats = 10240 B

__device__ __forceinline__ float ftanh(float x) {
  float e = exp2f(x * 2.8853900817779268f);   // exp(2x) via exp2
  return 1.0f - 2.0f * __builtin_amdgcn_rcpf(e + 1.0f);
}

// ---------------- prep: pack weights in per-wave consumption order ----------
__global__ __launch_bounds__(256) void prep_kernel(
    const float* __restrict__ A,   const float* __restrict__ Bm,
    const float* __restrict__ Cm,  const float* __restrict__ Dm,
    const float* __restrict__ pW1, const float* __restrict__ pb1,
    const float* __restrict__ pW2, const float* __restrict__ pb2,
    const float* __restrict__ pW3, const float* __restrict__ pb3,
    const float* __restrict__ zW1, const float* __restrict__ zb1,
    const float* __restrict__ zW2, const float* __restrict__ zb2,
    const float* __restrict__ zW3, const float* __restrict__ zb3,
    float* __restrict__ ws)
{
  const int tid = threadIdx.x;
  // L1: waves 0,1 -> Z rows 0-4 / 5-9 ; waves 2,3 -> phi rows 0-4 / 5-9
  for (int c = tid; c < 20; c += 256) {
    int q = c / 5, r = c % 5;
    const float* W = (q < 2) ? zW1 : pW1;
    const float* b = (q < 2) ? zb1 : pb1;
    int row = 5 * (q & 1) + r;
    float* d = ws + WS_L1 + c * 20;
    d[0] = b[row];
    for (int k = 0; k < 17; ++k) d[1 + k] = W[k * 10 + row];
    d[18] = 0.f; d[19] = 0.f;
  }
  // L2
  for (int c = tid; c < 20; c += 256) {
    int q = c / 5, r = c % 5;
    const float* W = (q < 2) ? zW2 : pW2;
    const float* b = (q < 2) ? zb2 : pb2;
    int row = 5 * (q & 1) + r;
    float* d = ws + WS_L2 + c * 12;
    d[0] = b[row];
    for (int k = 0; k < 10; ++k) d[1 + k] = W[k * 10 + row];
    d[11] = 0.f;
  }
  // L3: waves 0,1 -> Zv rows (8 each, z-MLP); waves 2,3 -> u rows (4 each, phi)
  for (int c = tid; c < 32; c += 256) {
    int q = c / 8, r = c % 8;
    float* d = ws + WS_L3 + c * 12;
    if (q < 2) {
      int row = 8 * q + r;
      d[0] = zb3[row];
      for (int k = 0; k < 10; ++k) d[1 + k] = zW3[k * 16 + row];
      d[11] = 0.f;
    } else if (r < 4) {
      int row = 4 * (q - 2) + r;
      d[0] = pb3[row];
      for (int k = 0; k < 10; ++k) d[1 + k] = pW3[k * 8 + row];
      d[11] = 0.f;
    }
  }
  // UPD: per state row i: A row, B row, C row, D row, A col, C col
  for (int i = tid; i < 16; i += 256) {
    float* d = ws + WS_UPD + i * 80;
    for (int j = 0; j < 16; ++j) d[j]      = A [i * 16 + j];
    for (int j = 0; j < 8;  ++j) d[16 + j] = Bm[i * 8  + j];
    for (int j = 0; j < 16; ++j) d[24 + j] = Cm[i * 16 + j];
    for (int j = 0; j < 8;  ++j) d[40 + j] = Dm[i * 8  + j];
    for (int j = 0; j < 16; ++j) d[48 + j] = A [j * 16 + i];
    for (int j = 0; j < 16; ++j) d[64 + j] = Cm[j * 16 + i];
  }
  // DH: per control row i: B col, D col
  for (int i = tid; i < 8; i += 256) {
    float* d = ws + WS_DH + i * 32;
    for (int j = 0; j < 16; ++j) d[j]      = Bm[j * 8 + i];
    for (int j = 0; j < 16; ++j) d[16 + j] = Dm[j * 8 + i];
  }
}

// ---------------- main: 4 waves / 64 elements per block ---------------------
__global__ __launch_bounds__(256) void bsde_kernel(
    const float* __restrict__ dw,  const float* __restrict__ X0,
    const float* __restrict__ yW1, const float* __restrict__ yb1,
    const float* __restrict__ yW2, const float* __restrict__ yb2,
    const float* __restrict__ yW3, const float* __restrict__ yb3,
    const float* __restrict__ ws,  float* __restrict__ out)
{
  // Odd float4 strides (9, 3, 7) -> conflict-free b128 LDS traffic.
  __shared__ float XY [64][36];   // X: 0..15, Y: 16..31
  __shared__ float H1Z[64][12], H1P[64][12];
  __shared__ float H2Z[64][12], H2P[64][12];
  __shared__ float ZU [64][28];   // Zv: 0..15, u: 16..23

  const int lane = threadIdx.x & 63;
  const int q    = __builtin_amdgcn_readfirstlane((int)(threadIdx.x >> 6));
  const int e    = blockIdx.x * 64 + lane;

  const float* Wl1 = ws + WS_L1  + q * 100;
  const float* Wl2 = ws + WS_L2  + q * 60;
  const float* Wl3 = ws + WS_L3  + q * 96;
  const float* Wup = ws + WS_UPD + q * 320;
  const float* Wdh = ws + WS_DH  + q * 64;

  float (*H1)[12] = (q < 2) ? H1Z : H1P;
  float (*H2)[12] = (q < 2) ? H2Z : H2P;
  const int ro = (q & 1) * 5;

  // ---- X0 load + Y0 MLP (computed redundantly by every wave, one-time) ----
  float xf[16];
#pragma unroll
  for (int i = 0; i < 16; ++i) xf[i] = X0[e * 16 + i];

  float h1t[10], h2t[10], yf[16];
#pragma unroll
  for (int r = 0; r < 10; ++r) {
    float s = yb1[r];
#pragma unroll
    for (int k = 0; k < 16; ++k) s += xf[k] * yW1[k * 10 + r];
    h1t[r] = ftanh(s);
  }
#pragma unroll
  for (int r = 0; r < 10; ++r) {
    float s = yb2[r];
#pragma unroll
    for (int k = 0; k < 10; ++k) s += h1t[k] * yW2[k * 10 + r];
    h2t[r] = ftanh(s);
  }
#pragma unroll
  for (int r = 0; r < 16; ++r) {
    float s = yb3[r];
#pragma unroll
    for (int k = 0; k < 10; ++k) s += h2t[k] * yW3[k * 16 + r];
    yf[r] = s;
  }

  // R2 FIX: seed XY before the time loop. The state-update phase reads
  // XY[lane][i] / XY[lane][16+i] for its own rows at EVERY t, including t=0;
  // in R1 the first write only happened at the END of iteration 0 ->
  // uninitialized-LDS garbage. yf is bit-identical across waves, so one
  // wave writes; the first in-loop __syncthreads orders it before any read.
  if (q == 0) {
#pragma unroll
    for (int k = 0; k < 16; ++k) {
      XY[lane][k]      = xf[k];
      XY[lane][16 + k] = yf[k];
    }
  }

  float lcp = 0.0f;

  // ------------------------------- time loop -------------------------------
#pragma unroll 1
  for (int t = 0; t < kT; ++t) {
    const float tv  = (float)t * kDT;
    const float wt  = (t == 0 || t == kT - 1) ? 1.0f : 2.0f;
    const float dwv = dw[t * kB + e];

    // L1 (own MLP, 5 rows): packed row = [bias, w_t, w_x0..w_x15]
    float a1[5];
#pragma unroll
    for (int r = 0; r < 5; ++r) {
      const float* w = Wl1 + r * 20;
      float s = w[0] + tv * w[1];
#pragma unroll
      for (int k = 0; k < 16; ++k) s += xf[k] * w[2 + k];
      a1[r] = ftanh(s);
    }
#pragma unroll
    for (int r = 0; r < 5; ++r) H1[lane][ro + r] = a1[r];
    __syncthreads();
    float hh[10];
#pragma unroll
    for (int k = 0; k < 10; ++k) hh[k] = H1[lane][k];

    // L2 (own MLP, 5 rows)
    float a2[5];
#pragma unroll
    for (int r = 0; r < 5; ++r) {
      const float* w = Wl2 + r * 12;
      float s = w[0];
#pragma unroll
      for (int k = 0; k < 10; ++k) s += hh[k] * w[1 + k];
      a2[r] = ftanh(s);
    }
#pragma unroll
    for (int r = 0; r < 5; ++r) H2[lane][ro + r] = a2[r];
    __syncthreads();
#pragma unroll
    for (int k = 0; k < 10; ++k) hh[k] = H2[lane][k];

    // L3: waves 0,1 -> 8 Zv rows; waves 2,3 -> 4 u rows
    if (q < 2) {
#pragma unroll
      for (int r = 0; r < 8; ++r) {
        const float* w = Wl3 + r * 12;
        float s = w[0];
#pragma unroll
        for (int k = 0; k < 10; ++k) s += hh[k] * w[1 + k];
        ZU[lane][8 * q + r] = s;
      }
    } else {
#pragma unroll
      for (int r = 0; r < 4; ++r) {
        const float* w = Wl3 + r * 12;
        float s = w[0];
#pragma unroll
        for (int k = 0; k < 10; ++k) s += hh[k] * w[1 + k];
        ZU[lane][16 + 4 * (q - 2) + r] = s;
      }
    }
    __syncthreads();
    float zv[16], uf[8];
#pragma unroll
    for (int k = 0; k < 16; ++k) zv[k] = ZU[lane][k];
#pragma unroll
    for (int k = 0; k < 8; ++k)  uf[k] = ZU[lane][16 + k];

    // State updates: rows i = 4q..4q+3 (runtime-row values via LDS, not
    // runtime-indexed register arrays -> no scratch spills)
    float Xn[4], Yn[4];
#pragma unroll
    for (int r = 0; r < 4; ++r) {
      const int i = 4 * q + r;
      const float* w = Wup + r * 80;
      float dx = kGamma, fx = kSigma;
#pragma unroll
      for (int j = 0; j < 16; ++j) dx += w[j] * xf[j];
#pragma unroll
      for (int j = 0; j < 8;  ++j) dx += w[16 + j] * uf[j];
#pragma unroll
      for (int j = 0; j < 16; ++j) fx += w[24 + j] * xf[j];
#pragma unroll
      for (int j = 0; j < 8;  ++j) fx += w[40 + j] * uf[j];
      const float xi = XY[lane][i];        // seeded pre-loop, rewritten each t
      const float yi = XY[lane][16 + i];
      const float zi = ZU[lane][i];
      float dy = xi;
#pragma unroll
      for (int j = 0; j < 16; ++j) dy += w[48 + j] * yf[j] + w[64 + j] * zv[j];
      Xn[r] = xi + kDT * dx + dwv * fx;
      Yn[r] = yi - kDT * dy + dwv * zi;
    }

    // dH rows i = 2q, 2q+1
    float s2 = 0.0f;
#pragma unroll
    for (int r = 0; r < 2; ++r) {
      const int i = 2 * q + r;
      const float* w = Wdh + r * 32;
      float dh = ZU[lane][16 + i];         // u[i]
#pragma unroll
      for (int j = 0; j < 16; ++j) dh += w[j] * yf[j] + w[16 + j] * zv[j];
      s2 += dh * dh;
    }
    lcp += (0.5f * kDT * kTau * kTau) * wt * s2;

    // Exchange updated state (each wave owns rows 4q..4q+3; reads of those
    // rows this iteration are wave-local, so no cross-wave hazard pre-barrier)
#pragma unroll
    for (int r = 0; r < 4; ++r) XY[lane][4 * q + r]      = Xn[r];
#pragma unroll
    for (int r = 0; r < 4; ++r) XY[lane][16 + 4 * q + r] = Yn[r];
    __syncthreads();
#pragma unroll
    for (int k = 0; k < 16; ++k) xf[k] = XY[lane][k];
#pragma unroll
    for (int k = 0; k < 16; ++k) yf[k] = XY[lane][16 + k];
  }

  // ---- losses ----
  float bp = 0.0f;
  if (q == 0) {
#pragma unroll
    for (int i = 0; i < 16; ++i) { float d = yf[i] - xf[i]; bp += d * d; }
  }
#pragma unroll
  for (int s = 32; s > 0; s >>= 1) {
    bp  += __shfl_down(bp,  s, 64);
    lcp += __shfl_down(lcp, s, 64);
  }
  if (lane == 0) {
    if (q == 0) atomicAdd(&out[0], bp * (1.0f / (float)kB));
    atomicAdd(&out[1], lcp * (1.0f / (float)kB));
  }
}

} // namespace

extern "C" void kernel_launch(void* const* d_in, const int* in_sizes, int n_in,
                              void* d_out, int out_size, void* d_ws, size_t ws_size,
                              hipStream_t stream) {
  (void)in_sizes; (void)n_in; (void)ws_size; (void)out_size;

  const float* dw  = (const float*)d_in[0];
  const float* X0  = (const float*)d_in[1];
  const float* A   = (const float*)d_in[2];
  const float* Bm  = (const float*)d_in[3];
  const float* Cm  = (const float*)d_in[4];
  const float* Dm  = (const float*)d_in[5];
  const float* pW1 = (const float*)d_in[6];
  const float* pb1 = (const float*)d_in[7];
  const float* pW2 = (const float*)d_in[8];
  const float* pb2 = (const float*)d_in[9];
  const float* pW3 = (const float*)d_in[10];
  const float* pb3 = (const float*)d_in[11];
  const float* zW1 = (const float*)d_in[12];
  const float* zb1 = (const float*)d_in[13];
  const float* zW2 = (const float*)d_in[14];
  const float* zb2 = (const float*)d_in[15];
  const float* zW3 = (const float*)d_in[16];
  const float* zb3 = (const float*)d_in[17];
  const float* yW1 = (const float*)d_in[18];
  const float* yb1 = (const float*)d_in[19];
  const float* yW2 = (const float*)d_in[20];
  const float* yb2 = (const float*)d_in[21];
  const float* yW3 = (const float*)d_in[22];
  const float* yb3 = (const float*)d_in[23];
  float* out = (float*)d_out;
  float* ws  = (float*)d_ws;

  hipMemsetAsync(out, 0, 2 * sizeof(float), stream);

  prep_kernel<<<1, 256, 0, stream>>>(
      A, Bm, Cm, Dm,
      pW1, pb1, pW2, pb2, pW3, pb3,
      zW1, zb1, zW2, zb2, zW3, zb3, ws);

  bsde_kernel<<<kB / 64, 256, 0, stream>>>(
      dw, X0, yW1, yb1, yW2, yb2, yW3, yb3, ws, out);
}